// Round 5
// baseline (103.159 us; speedup 1.0000x reference)
//
#include <hip/hip_runtime.h>

// Lovasz-Softmax without sorting (exact up to bin-midpoint error <= 0.5/NB):
//  - ties in the error value don't change the loss (telescoping within
//    equal-error groups)
//  - jaccard is monotone along the sorted order with total variation 1, so
//    binning errors and using midpoints has per-class error <= 4.9e-4 (NB=1024).
// R5: single dispatch, NO grid.sync (R4: two grid.syncs cost ~50us on 8 XCDs).
// Ordering is one-way and cheap:
//   - block 0 zeroes ghist+done, __threadfence, publishes MAGIC flag (release).
//   - every block acquires the flag right before its LDS->global flush (by
//     then the flag has been set for ~10us -> no actual spinning).
//   - last-block ticket (acq_rel atomicAdd) elects the scanner block; it
//     reads the summed histogram, computes the loss, writes out, resets flag.

constexpr int NCLS = 6;
constexpr int HW   = 512 * 512;
constexpr int NPIX = 8 * HW;
constexpr int NB   = 1024;       // bin width 1/1024 -> loss error <= 4.9e-4
constexpr int NROWS = 2 * NCLS;  // rows 0..5: non-fg (p_c, c!=lab); 6..11: fg (1-p_lab)
constexpr int HIST_WORDS = NROWS * NB;   // 12288 u32 = 48 KB

constexpr int GBLK = 256;
constexpr int GTHR = 1024;
constexpr unsigned MAGIC = 0x5AFE0001u;  // poison 0xAAAAAAAA != MAGIC

__global__ __launch_bounds__(GTHR) void lovasz_onepass(
    const float* __restrict__ logits, const int* __restrict__ labels,
    unsigned* __restrict__ ghist, float* __restrict__ out) {
  unsigned* flag = ghist + HIST_WORDS;
  unsigned* done = ghist + HIST_WORDS + 1;

  __shared__ unsigned lh[HIST_WORDS];        // 48 KB
  __shared__ unsigned s_ticket;
  __shared__ double   sloss[NCLS];
  __shared__ unsigned spres[NCLS];

  const int t = threadIdx.x;

  // ---- block 0: zero global accumulator, then publish (release) ----
  if (blockIdx.x == 0) {
    for (int i = t; i < HIST_WORDS; i += GTHR) ghist[i] = 0u;
    if (t == 0) *done = 0u;
    __threadfence();                         // device-scope: zeros visible
    __syncthreads();
    if (t == 0)
      __hip_atomic_store(flag, MAGIC, __ATOMIC_RELEASE, __HIP_MEMORY_SCOPE_AGENT);
  }

  // ---- LDS-private histogram ----
  for (int i = t; i < HIST_WORDS; i += GTHR) lh[i] = 0u;
  __syncthreads();

  const int nquads = NPIX / 4;
  for (int q = blockIdx.x * GTHR + t; q < nquads; q += GBLK * GTHR) {
    int n4 = q << 2;
    int b  = n4 >> 18;                       // / HW
    int hw = n4 & (HW - 1);

    int4 lab4 = *reinterpret_cast<const int4*>(labels + n4);
    int labs[4] = {lab4.x, lab4.y, lab4.z, lab4.w};
    if ((lab4.x | lab4.y | lab4.z | lab4.w) == 0) continue;  // all ignored

    float xx[NCLS][4];
    size_t base = ((size_t)b * NCLS) << 18;
#pragma unroll
    for (int c = 0; c < NCLS; ++c) {
      float4 v = *reinterpret_cast<const float4*>(logits + base + ((size_t)c << 18) + hw);
      xx[c][0] = v.x; xx[c][1] = v.y; xx[c][2] = v.z; xx[c][3] = v.w;
    }

#pragma unroll
    for (int j = 0; j < 4; ++j) {
      int lab = labs[j];
      if (lab == 0) continue;                // IGNORE: contributes exactly 0
      float m = xx[0][j];
#pragma unroll
      for (int c = 1; c < NCLS; ++c) m = fmaxf(m, xx[c][j]);
      float e[NCLS];
      float s = 0.f;
#pragma unroll
      for (int c = 0; c < NCLS; ++c) { e[c] = __expf(xx[c][j] - m); s += e[c]; }
      float inv = 1.0f / s;
#pragma unroll
      for (int c = 0; c < NCLS; ++c) {
        float p   = e[c] * inv;
        bool  fg  = (c == lab);
        float err = fg ? 1.0f - p : p;
        int bin = (int)(err * (float)NB);
        bin = bin < 0 ? 0 : (bin > NB - 1 ? NB - 1 : bin);
        int row = fg ? NCLS + c : c;
        atomicAdd(&lh[row * NB + bin], 1u);
      }
    }
  }
  __syncthreads();

  // ---- wait (normally already satisfied) for the zero-publish ----
  if (t == 0) {
    while (__hip_atomic_load(flag, __ATOMIC_ACQUIRE, __HIP_MEMORY_SCOPE_AGENT) != MAGIC)
      __builtin_amdgcn_s_sleep(8);
  }
  __syncthreads();

  // ---- flush LDS -> global (device-scope atomics) ----
  for (int i = t; i < HIST_WORDS; i += GTHR) {
    unsigned v = lh[i];
    if (v) atomicAdd(&ghist[i], v);
  }
  __threadfence();
  __syncthreads();
  if (t == 0)
    s_ticket = __hip_atomic_fetch_add(done, 1u, __ATOMIC_ACQ_REL, __HIP_MEMORY_SCOPE_AGENT);
  __syncthreads();
  if (s_ticket != GBLK - 1) return;          // not the last block

  // ---- last block: 6-wave scan (wave w = class w) + final average ----
  __threadfence();                           // acquire side for plain reads
  if (t < 64 * NCLS) {
    const int wave = t >> 6;
    const int lane = t & 63;
    const unsigned* ha = ghist + wave * NB;          // non-fg contributions
    const unsigned* hf = ghist + (NCLS + wave) * NB; // fg contributions
    const int base = NB - 16 - lane * 16;            // lane 0 -> highest bins

    unsigned a[16], f[16];
#pragma unroll
    for (int i = 0; i < 16; ++i) {
      a[i] = __hip_atomic_load(&ha[base + i], __ATOMIC_RELAXED, __HIP_MEMORY_SCOPE_AGENT);
      f[i] = __hip_atomic_load(&hf[base + i], __ATOMIC_RELAXED, __HIP_MEMORY_SCOPE_AGENT);
    }

    unsigned dn = 0, df = 0;
#pragma unroll
    for (int i = 0; i < 16; ++i) { dn += a[i] + f[i]; df += f[i]; }

    unsigned sn = dn, sf = df;                       // inclusive wave scan
    for (int off = 1; off < 64; off <<= 1) {
      unsigned tn = __shfl_up(sn, off);
      unsigned tf = __shfl_up(sf, off);
      if (lane >= off) { sn += tn; sf += tf; }
    }
    const unsigned total_f = __shfl(sf, 63);         // gts
    unsigned n  = sn - dn;                           // exclusive prefix
    unsigned ff = sf - df;

    double contrib = 0.0;
    if (total_f > 0) {
      const double gts = (double)total_f;
      for (int i = 15; i >= 0; --i) {                // descending within chunk
        unsigned dnb = a[i] + f[i];
        if (!dnb) continue;
        unsigned dfb = f[i];
        double ub = gts + (double)n - (double)ff;
        double jb = 1.0 - (gts - (double)ff) / ub;
        n += dnb; ff += dfb;
        double ua = gts + (double)n - (double)ff;
        double ja = 1.0 - (gts - (double)ff) / ua;
        contrib += ((double)(base + i) + 0.5) * (1.0 / (double)NB) * (ja - jb);
      }
    }
    for (int off = 32; off > 0; off >>= 1) contrib += __shfl_down(contrib, off);
    if (lane == 0) { sloss[wave] = contrib; spres[wave] = total_f; }
  }
  __syncthreads();
  if (t == 0) {
    double s = 0.0, np = 0.0;
    for (int k = 0; k < NCLS; ++k)
      if (spres[k]) { s += sloss[k]; np += 1.0; }
    out[0] = (float)(s / (np > 0.0 ? np : 1.0));
    // reset protocol state for the next call / replay
    __hip_atomic_store(flag, 0u, __ATOMIC_RELEASE, __HIP_MEMORY_SCOPE_AGENT);
  }
}

extern "C" void kernel_launch(void* const* d_in, const int* in_sizes, int n_in,
                              void* d_out, int out_size, void* d_ws, size_t ws_size,
                              hipStream_t stream) {
  const float* logits = (const float*)d_in[0];
  const int*   labels = (const int*)d_in[1];
  unsigned*    ghist  = (unsigned*)d_ws;

  lovasz_onepass<<<GBLK, GTHR, 0, stream>>>(logits, labels, ghist, (float*)d_out);
}

// Round 6
// 29.757 us; speedup vs baseline: 3.4668x; 3.4668x over previous
//
#include <hip/hip_runtime.h>

// Lovasz-Softmax without sorting (exact up to bin-midpoint error <= 0.5/NB):
//  - ties in the error value don't change the loss (telescoping within
//    equal-error groups)
//  - jaccard is monotone along the sorted order with total variation 1, so
//    binning errors and using midpoints has per-class error <= 0.5/NB.
// R6: back to the proven 3-dispatch structure (single-dispatch protocols cost
// 60-80us on 8 XCDs). Fixes vs R3:
//  - grid 512 (was 256): 2 resident 1024-thread blocks per CU -> 32 waves/CU
//    for HBM latency hiding (R2-R5 ran at 16).
//  - NB 256 (was 1024): error bound 2e-3 << 1.67e-2 threshold; LDS 12KB,
//    per-block zero/flush work /4, global flush atomics 1.57M (was 3.1M).

constexpr int NCLS = 6;
constexpr int HW   = 512 * 512;
constexpr int NPIX = 8 * HW;
constexpr int NB   = 256;        // bin width 1/256 -> loss error <= 2.0e-3
constexpr int NROWS = 2 * NCLS;  // rows 0..5: non-fg (p_c, c!=lab); 6..11: fg (1-p_lab)
constexpr int HIST_WORDS = NROWS * NB;   // 3072 u32 = 12 KB

constexpr int HBLK = 512;        // 1 quad per thread exactly
constexpr int HTHR = 1024;

__global__ __launch_bounds__(1024) void lovasz_zero(unsigned* __restrict__ g) {
  int i = blockIdx.x * 1024 + threadIdx.x;
  if (i < HIST_WORDS) g[i] = 0u;
}

__global__ __launch_bounds__(HTHR) void lovasz_hist(
    const float* __restrict__ logits, const int* __restrict__ labels,
    unsigned* __restrict__ ghist) {
  __shared__ unsigned lh[HIST_WORDS];        // 12 KB
  for (int i = threadIdx.x; i < HIST_WORDS; i += HTHR) lh[i] = 0u;
  __syncthreads();

  const int q  = blockIdx.x * HTHR + threadIdx.x;   // 0 .. 524287
  const int n4 = q << 2;
  const int b  = n4 >> 18;                   // / HW
  const int hw = n4 & (HW - 1);

  int4 lab4 = *reinterpret_cast<const int4*>(labels + n4);
  int labs[4] = {lab4.x, lab4.y, lab4.z, lab4.w};
  if ((lab4.x | lab4.y | lab4.z | lab4.w) != 0) {   // else: all ignored, skip
    float xx[NCLS][4];
    size_t base = ((size_t)b * NCLS) << 18;
#pragma unroll
    for (int c = 0; c < NCLS; ++c) {
      float4 v = *reinterpret_cast<const float4*>(logits + base + ((size_t)c << 18) + hw);
      xx[c][0] = v.x; xx[c][1] = v.y; xx[c][2] = v.z; xx[c][3] = v.w;
    }

#pragma unroll
    for (int j = 0; j < 4; ++j) {
      int lab = labs[j];
      if (lab == 0) continue;                // IGNORE: contributes exactly 0
      float m = xx[0][j];
#pragma unroll
      for (int c = 1; c < NCLS; ++c) m = fmaxf(m, xx[c][j]);
      float e[NCLS];
      float s = 0.f;
#pragma unroll
      for (int c = 0; c < NCLS; ++c) { e[c] = __expf(xx[c][j] - m); s += e[c]; }
      float inv = 1.0f / s;
#pragma unroll
      for (int c = 0; c < NCLS; ++c) {
        float p   = e[c] * inv;
        bool  fg  = (c == lab);
        float err = fg ? 1.0f - p : p;
        int bin = (int)(err * (float)NB);
        bin = bin < 0 ? 0 : (bin > NB - 1 ? NB - 1 : bin);
        int row = fg ? NCLS + c : c;
        atomicAdd(&lh[row * NB + bin], 1u);
      }
    }
  }

  __syncthreads();
  for (int i = threadIdx.x; i < HIST_WORDS; i += HTHR) {
    unsigned v = lh[i];
    if (v) atomicAdd(&ghist[i], v);
  }
}

// One block, 6 waves: wave w handles class w. Each lane owns 4 contiguous
// bins; lane 0 has the highest-error bins so lane order == descending order.
__global__ __launch_bounds__(64 * NCLS) void lovasz_scanfinal(
    const unsigned* __restrict__ ghist, float* __restrict__ out) {
  const int wave = threadIdx.x >> 6;       // class index
  const int lane = threadIdx.x & 63;
  const unsigned* ha = ghist + wave * NB;          // non-fg contributions
  const unsigned* hf = ghist + (NCLS + wave) * NB; // fg contributions
  constexpr int K = NB / 64;                       // 4 bins per lane
  const int base = NB - K - lane * K;              // lane 0 -> highest bins

  unsigned a[K], f[K];
#pragma unroll
  for (int i = 0; i < K; ++i) { a[i] = ha[base + i]; f[i] = hf[base + i]; }

  unsigned dn = 0, df = 0;
#pragma unroll
  for (int i = 0; i < K; ++i) { dn += a[i] + f[i]; df += f[i]; }

  unsigned sn = dn, sf = df;               // inclusive wave scan
  for (int off = 1; off < 64; off <<= 1) {
    unsigned tn = __shfl_up(sn, off);
    unsigned tf = __shfl_up(sf, off);
    if (lane >= off) { sn += tn; sf += tf; }
  }
  const unsigned total_f = __shfl(sf, 63); // gts
  unsigned n  = sn - dn;                   // exclusive prefix (larger errors)
  unsigned ff = sf - df;

  double contrib = 0.0;
  if (total_f > 0) {
    const double gts = (double)total_f;
    for (int i = K - 1; i >= 0; --i) {     // descending bins within chunk
      unsigned dnb = a[i] + f[i];
      if (!dnb) continue;
      unsigned dfb = f[i];
      double ub = gts + (double)n - (double)ff;
      double jb = 1.0 - (gts - (double)ff) / ub;
      n += dnb; ff += dfb;
      double ua = gts + (double)n - (double)ff;
      double ja = 1.0 - (gts - (double)ff) / ua;
      contrib += ((double)(base + i) + 0.5) * (1.0 / (double)NB) * (ja - jb);
    }
  }
  for (int off = 32; off > 0; off >>= 1) contrib += __shfl_down(contrib, off);

  __shared__ double   sloss[NCLS];
  __shared__ unsigned spres[NCLS];
  if (lane == 0) { sloss[wave] = contrib; spres[wave] = total_f; }
  __syncthreads();
  if (threadIdx.x == 0) {
    double s = 0.0, np = 0.0;
    for (int k = 0; k < NCLS; ++k)
      if (spres[k]) { s += sloss[k]; np += 1.0; }
    out[0] = (float)(s / (np > 0.0 ? np : 1.0));
  }
}

extern "C" void kernel_launch(void* const* d_in, const int* in_sizes, int n_in,
                              void* d_out, int out_size, void* d_ws, size_t ws_size,
                              hipStream_t stream) {
  const float* logits = (const float*)d_in[0];
  const int*   labels = (const int*)d_in[1];
  unsigned*    ghist  = (unsigned*)d_ws;

  lovasz_zero<<<(HIST_WORDS + 1023) / 1024, 1024, 0, stream>>>(ghist);
  lovasz_hist<<<HBLK, HTHR, 0, stream>>>(logits, labels, ghist);
  lovasz_scanfinal<<<1, 64 * NCLS, 0, stream>>>(ghist, (float*)d_out);
}

// Round 7
// 26.376 us; speedup vs baseline: 3.9111x; 1.1282x over previous
//
#include <hip/hip_runtime.h>

// Lovasz-Softmax without sorting (exact up to bin-midpoint error <= 0.5/NB):
//  - ties in the error don't change the loss (telescoping within equal-error
//    groups); jaccard is monotone with total variation 1 -> binning to NB bins
//    with midpoints has per-class error <= 0.5/NB (= 2e-3 at NB=256, measured 0).
// R7 vs R6:
//  - 4 LDS sub-histograms selected by lane&3, copy stride 3080 words
//    (3080%32==8 -> same bin maps to 4 distinct banks): cuts intra-wave
//    same-address atomic serialization on hot bins ~4x.
//  - global flush spread over 8 regions (blockIdx&7): 8x fewer same-address
//    L2 atomic collisions. scanfinal sums the 8 regions.

constexpr int NCLS = 6;
constexpr int HW   = 512 * 512;
constexpr int NPIX = 8 * HW;
constexpr int NB   = 256;        // bin width 1/256 -> loss error <= 2.0e-3
constexpr int NROWS = 2 * NCLS;  // rows 0..5: non-fg (p_c); 6..11: fg (1-p_lab)
constexpr int HIST_WORDS = NROWS * NB;     // 3072
constexpr int NSUB = 4;
constexpr int SUBSTRIDE = HIST_WORDS + 8;  // 3080; %32==8 -> bank-shifted copies
constexpr int NREG = 8;                    // global flush regions
constexpr int GHIST_WORDS = NREG * HIST_WORDS;  // 24576

constexpr int HBLK = 512;        // 1 quad per thread exactly
constexpr int HTHR = 1024;

__global__ __launch_bounds__(1024) void lovasz_zero(unsigned* __restrict__ g) {
  int i = blockIdx.x * 1024 + threadIdx.x;
  if (i < GHIST_WORDS) g[i] = 0u;
}

__global__ __launch_bounds__(HTHR) void lovasz_hist(
    const float* __restrict__ logits, const int* __restrict__ labels,
    unsigned* __restrict__ ghist) {
  __shared__ unsigned lh[NSUB * SUBSTRIDE];  // ~49.3 KB
  for (int i = threadIdx.x; i < NSUB * SUBSTRIDE; i += HTHR) lh[i] = 0u;
  __syncthreads();

  const int sub = (threadIdx.x & 3) * SUBSTRIDE;    // lane-based sub-histogram
  const int q  = blockIdx.x * HTHR + threadIdx.x;   // 0 .. 524287
  const int n4 = q << 2;
  const int b  = n4 >> 18;                   // / HW
  const int hw = n4 & (HW - 1);

  int4 lab4 = *reinterpret_cast<const int4*>(labels + n4);
  int labs[4] = {lab4.x, lab4.y, lab4.z, lab4.w};
  if ((lab4.x | lab4.y | lab4.z | lab4.w) != 0) {   // else all ignored: skip
    float xx[NCLS][4];
    size_t base = ((size_t)b * NCLS) << 18;
#pragma unroll
    for (int c = 0; c < NCLS; ++c) {
      float4 v = *reinterpret_cast<const float4*>(logits + base + ((size_t)c << 18) + hw);
      xx[c][0] = v.x; xx[c][1] = v.y; xx[c][2] = v.z; xx[c][3] = v.w;
    }

#pragma unroll
    for (int j = 0; j < 4; ++j) {
      int lab = labs[j];
      if (lab == 0) continue;                // IGNORE: contributes exactly 0
      float m = xx[0][j];
#pragma unroll
      for (int c = 1; c < NCLS; ++c) m = fmaxf(m, xx[c][j]);
      float e[NCLS];
      float s = 0.f;
#pragma unroll
      for (int c = 0; c < NCLS; ++c) { e[c] = __expf(xx[c][j] - m); s += e[c]; }
      float inv = 1.0f / s;
#pragma unroll
      for (int c = 0; c < NCLS; ++c) {
        float p   = e[c] * inv;
        bool  fg  = (c == lab);
        float err = fg ? 1.0f - p : p;
        int bin = (int)(err * (float)NB);
        bin = bin < 0 ? 0 : (bin > NB - 1 ? NB - 1 : bin);
        int row = fg ? NCLS + c : c;
        atomicAdd(&lh[sub + row * NB + bin], 1u);
      }
    }
  }

  __syncthreads();
  unsigned* gbase = ghist + (blockIdx.x & (NREG - 1)) * HIST_WORDS;
  for (int i = threadIdx.x; i < HIST_WORDS; i += HTHR) {
    unsigned v = lh[i] + lh[SUBSTRIDE + i] + lh[2 * SUBSTRIDE + i] + lh[3 * SUBSTRIDE + i];
    if (v) atomicAdd(&gbase[i], v);
  }
}

// One block, 6 waves: wave w handles class w. Each lane owns 4 contiguous
// bins; lane 0 has the highest-error bins so lane order == descending order.
__global__ __launch_bounds__(64 * NCLS) void lovasz_scanfinal(
    const unsigned* __restrict__ ghist, float* __restrict__ out) {
  const int wave = threadIdx.x >> 6;       // class index
  const int lane = threadIdx.x & 63;
  constexpr int K = NB / 64;               // 4 bins per lane
  const int base = NB - K - lane * K;      // lane 0 -> highest bins

  unsigned a[K], f[K];
#pragma unroll
  for (int i = 0; i < K; ++i) {
    unsigned sa = 0, sf2 = 0;
#pragma unroll
    for (int r = 0; r < NREG; ++r) {
      sa  += ghist[r * HIST_WORDS + wave * NB + base + i];
      sf2 += ghist[r * HIST_WORDS + (NCLS + wave) * NB + base + i];
    }
    a[i] = sa; f[i] = sf2;
  }

  unsigned dn = 0, df = 0;
#pragma unroll
  for (int i = 0; i < K; ++i) { dn += a[i] + f[i]; df += f[i]; }

  unsigned sn = dn, sf = df;               // inclusive wave scan
  for (int off = 1; off < 64; off <<= 1) {
    unsigned tn = __shfl_up(sn, off);
    unsigned tf = __shfl_up(sf, off);
    if (lane >= off) { sn += tn; sf += tf; }
  }
  const unsigned total_f = __shfl(sf, 63); // gts
  unsigned n  = sn - dn;                   // exclusive prefix (larger errors)
  unsigned ff = sf - df;

  double contrib = 0.0;
  if (total_f > 0) {
    const double gts = (double)total_f;
    for (int i = K - 1; i >= 0; --i) {     // descending bins within chunk
      unsigned dnb = a[i] + f[i];
      if (!dnb) continue;
      unsigned dfb = f[i];
      double ub = gts + (double)n - (double)ff;
      double jb = 1.0 - (gts - (double)ff) / ub;
      n += dnb; ff += dfb;
      double ua = gts + (double)n - (double)ff;
      double ja = 1.0 - (gts - (double)ff) / ua;
      contrib += ((double)(base + i) + 0.5) * (1.0 / (double)NB) * (ja - jb);
    }
  }
  for (int off = 32; off > 0; off >>= 1) contrib += __shfl_down(contrib, off);

  __shared__ double   sloss[NCLS];
  __shared__ unsigned spres[NCLS];
  if (lane == 0) { sloss[wave] = contrib; spres[wave] = total_f; }
  __syncthreads();
  if (threadIdx.x == 0) {
    double s = 0.0, np = 0.0;
    for (int k = 0; k < NCLS; ++k)
      if (spres[k]) { s += sloss[k]; np += 1.0; }
    out[0] = (float)(s / (np > 0.0 ? np : 1.0));
  }
}

extern "C" void kernel_launch(void* const* d_in, const int* in_sizes, int n_in,
                              void* d_out, int out_size, void* d_ws, size_t ws_size,
                              hipStream_t stream) {
  const float* logits = (const float*)d_in[0];
  const int*   labels = (const int*)d_in[1];
  unsigned*    ghist  = (unsigned*)d_ws;

  lovasz_zero<<<(GHIST_WORDS + 1023) / 1024, 1024, 0, stream>>>(ghist);
  lovasz_hist<<<HBLK, HTHR, 0, stream>>>(logits, labels, ghist);
  lovasz_scanfinal<<<1, 64 * NCLS, 0, stream>>>(ghist, (float*)d_out);
}